// Round 1
// baseline (2842.336 us; speedup 1.0000x reference)
//
#include <hip/hip_runtime.h>

#define FDIM 128

// ---------------------------------------------------------------------------
// Kernel 1: SpMM scatter  z[row[e]][:] += val[e] * x[col[e]][:]
// Half-wave (32 lanes) per edge, float4 per lane (32*4 = 128 features).
// ---------------------------------------------------------------------------
__global__ __launch_bounds__(256) void spmm_scatter(
    const int* __restrict__ row, const int* __restrict__ col,
    const float* __restrict__ val, const float* __restrict__ x,
    float* __restrict__ z, int nedges)
{
    int tid  = blockIdx.x * 256 + threadIdx.x;
    int half = tid >> 5;                    // global half-wave id
    int lane = tid & 31;
    int nhalf = (gridDim.x * 256) >> 5;

    for (int e = half; e < nedges; e += nhalf) {
        int   r = row[e];
        int   c = col[e];
        float v = val[e];
        float4 xv = *reinterpret_cast<const float4*>(
            x + (size_t)c * FDIM + lane * 4);
        float* zp = z + (size_t)r * FDIM + lane * 4;
        atomicAdd(zp + 0, v * xv.x);
        atomicAdd(zp + 1, v * xv.y);
        atomicAdd(zp + 2, v * xv.z);
        atomicAdd(zp + 3, v * xv.w);
    }
}

// ---------------------------------------------------------------------------
// Kernel 2: out[M,128] = z[M,128] @ W[128,128]   (fp32 vector ALU)
// Block: 256 threads, 64-row x 128-col output tile.
// z tile staged TRANSPOSED in LDS (sZt[k][r], ld=65 -> conflict-free b128
// reads of 4 consecutive rows). W staged in two 64-k chunks (ld=132, split
// columns c0 / c0+64 -> 2-way = free). Each thread: 4 rows x 8 cols.
// ---------------------------------------------------------------------------
__global__ __launch_bounds__(256, 2) void gemm_zw(
    const float* __restrict__ z, const float* __restrict__ w,
    float* __restrict__ out, int M)
{
    __shared__ float sZt[128 * 65];   // z^T tile: [k][r], 33.3 KB
    __shared__ float sW[64 * 132];    // W k-chunk: [k][c], 33.8 KB

    const int tidx = threadIdx.x;
    const int rowBase = blockIdx.x * 64;

    // ---- load z tile (64 rows x 128 k), store transposed ----
    #pragma unroll
    for (int i = 0; i < 8; ++i) {
        int idx = tidx + 256 * i;          // float4 index within 64x128 tile
        int r   = idx >> 5;                // 32 float4 per row
        int k4  = idx & 31;
        float4 v = make_float4(0.f, 0.f, 0.f, 0.f);
        if (rowBase + r < M)
            v = *reinterpret_cast<const float4*>(
                z + (size_t)(rowBase + r) * FDIM + k4 * 4);
        sZt[(k4 * 4 + 0) * 65 + r] = v.x;
        sZt[(k4 * 4 + 1) * 65 + r] = v.y;
        sZt[(k4 * 4 + 2) * 65 + r] = v.z;
        sZt[(k4 * 4 + 3) * 65 + r] = v.w;
    }

    const int ty = tidx >> 4;   // 0..15
    const int tx = tidx & 15;   // 0..15
    const int r0 = ty * 4;      // rows r0..r0+3
    const int c0 = tx * 4;      // cols c0..c0+3 and c0+64..c0+67

    float acc[4][8] = {};

    for (int kc = 0; kc < 128; kc += 64) {
        __syncthreads();        // sZt ready (first iter) / sW reads done (second)
        // ---- load W[kc..kc+63][0..127] ----
        #pragma unroll
        for (int i = 0; i < 8; ++i) {
            int idx = tidx + 256 * i;
            int k   = idx >> 5;
            int c4  = idx & 31;
            float4 v = *reinterpret_cast<const float4*>(
                w + (size_t)(kc + k) * FDIM + c4 * 4);
            *reinterpret_cast<float4*>(&sW[k * 132 + c4 * 4]) = v;
        }
        __syncthreads();

        #pragma unroll 8
        for (int kk = 0; kk < 64; ++kk) {
            int k = kc + kk;
            float4 zv = *reinterpret_cast<const float4*>(&sZt[k * 65 + r0]);
            float4 w0 = *reinterpret_cast<const float4*>(&sW[kk * 132 + c0]);
            float4 w1 = *reinterpret_cast<const float4*>(&sW[kk * 132 + c0 + 64]);
            float zr[4] = {zv.x, zv.y, zv.z, zv.w};
            float wv[8] = {w0.x, w0.y, w0.z, w0.w, w1.x, w1.y, w1.z, w1.w};
            #pragma unroll
            for (int i = 0; i < 4; ++i)
                #pragma unroll
                for (int j = 0; j < 8; ++j)
                    acc[i][j] += zr[i] * wv[j];
        }
    }

    // ---- store ----
    #pragma unroll
    for (int i = 0; i < 4; ++i) {
        int r = rowBase + r0 + i;
        if (r < M) {
            float4 o0 = make_float4(acc[i][0], acc[i][1], acc[i][2], acc[i][3]);
            float4 o1 = make_float4(acc[i][4], acc[i][5], acc[i][6], acc[i][7]);
            *reinterpret_cast<float4*>(out + (size_t)r * FDIM + c0)      = o0;
            *reinterpret_cast<float4*>(out + (size_t)r * FDIM + c0 + 64) = o1;
        }
    }
}

extern "C" void kernel_launch(void* const* d_in, const int* in_sizes, int n_in,
                              void* d_out, int out_size, void* d_ws, size_t ws_size,
                              hipStream_t stream) {
    const int*   row = (const int*)d_in[0];
    const int*   col = (const int*)d_in[1];
    const float* val = (const float*)d_in[2];
    const float* x   = (const float*)d_in[3];
    const float* w   = (const float*)d_in[4];
    float* out = (float*)d_out;

    const int nedges = in_sizes[0];
    const int M      = in_sizes[3] / FDIM;   // 100000

    float* z = (float*)d_ws;                  // M*128 floats = 51.2 MB scratch

    // z must be zeroed every call (ws re-poisoned to 0xAA before each launch)
    hipMemsetAsync(z, 0, (size_t)M * FDIM * sizeof(float), stream);

    spmm_scatter<<<2048, 256, 0, stream>>>(row, col, val, x, z, nedges);

    gemm_zw<<<(M + 63) / 64, 256, 0, stream>>>(z, w, out, M);
}

// Round 2
// 460.424 us; speedup vs baseline: 6.1733x; 6.1733x over previous
//
#include <hip/hip_runtime.h>

#define FDIM 128

// ---------------------------------------------------------------------------
// CSR build step 1: histogram of row counts
// ---------------------------------------------------------------------------
__global__ __launch_bounds__(256) void hist_rows(
    const int* __restrict__ row, int* __restrict__ counts, int nedges)
{
    int e = blockIdx.x * 256 + threadIdx.x;
    int stride = gridDim.x * 256;
    for (; e < nedges; e += stride)
        atomicAdd(&counts[row[e]], 1);
}

// ---------------------------------------------------------------------------
// CSR build step 2a: per-block exclusive scan (1024 elems/block of 256 thr)
// writes exclusive-scanned values to out, block total to partials[blk]
// ---------------------------------------------------------------------------
__global__ __launch_bounds__(256) void scan_block(
    const int* __restrict__ in, int* __restrict__ out,
    int* __restrict__ partials, int n)
{
    __shared__ int s[256];
    const int tid  = threadIdx.x;
    const int base = blockIdx.x * 1024 + tid * 4;

    int v[4];
    int t = 0;
    #pragma unroll
    for (int k = 0; k < 4; ++k) {
        v[k] = (base + k < n) ? in[base + k] : 0;
        t += v[k];
    }
    s[tid] = t;
    __syncthreads();
    #pragma unroll
    for (int off = 1; off < 256; off <<= 1) {
        int add = (tid >= off) ? s[tid - off] : 0;
        __syncthreads();
        s[tid] += add;
        __syncthreads();
    }
    int run = s[tid] - t;          // exclusive prefix of this thread's chunk
    #pragma unroll
    for (int k = 0; k < 4; ++k) {
        if (base + k < n) out[base + k] = run;
        run += v[k];
    }
    if (tid == 255) partials[blockIdx.x] = s[255];
}

// ---------------------------------------------------------------------------
// CSR build step 2b: exclusive scan of block totals (single block, <=1024)
// ---------------------------------------------------------------------------
__global__ __launch_bounds__(1024) void scan_partials(
    int* __restrict__ partials, int n)
{
    __shared__ int s[1024];
    const int tid = threadIdx.x;
    int t = (tid < n) ? partials[tid] : 0;
    s[tid] = t;
    __syncthreads();
    #pragma unroll
    for (int off = 1; off < 1024; off <<= 1) {
        int add = (tid >= off) ? s[tid - off] : 0;
        __syncthreads();
        s[tid] += add;
        __syncthreads();
    }
    if (tid < n) partials[tid] = s[tid] - t;   // exclusive
}

// ---------------------------------------------------------------------------
// CSR build step 2c: add scanned block offsets -> rowptr complete
// ---------------------------------------------------------------------------
__global__ __launch_bounds__(256) void scan_add(
    int* __restrict__ out, const int* __restrict__ partials, int n)
{
    const int add  = partials[blockIdx.x];
    const int base = blockIdx.x * 1024 + threadIdx.x * 4;
    #pragma unroll
    for (int k = 0; k < 4; ++k)
        if (base + k < n) out[base + k] += add;
}

// ---------------------------------------------------------------------------
// CSR build step 3: bucket fill. Destructively advances rowptr[r]; after this
// kernel rowptr[r] == original rowptr[r+1] (end pointer), so SpMM reads
// start = rowptr[r-1], end = rowptr[r]. col/val reordered into CSR order.
// ---------------------------------------------------------------------------
__global__ __launch_bounds__(256) void csr_fill(
    const int* __restrict__ row, const int* __restrict__ col,
    const float* __restrict__ val, int* __restrict__ rowptr,
    int* __restrict__ ecol, float* __restrict__ eval, int nedges)
{
    int e = blockIdx.x * 256 + threadIdx.x;
    int stride = gridDim.x * 256;
    for (; e < nedges; e += stride) {
        int r = row[e];
        int slot = atomicAdd(&rowptr[r], 1);
        ecol[slot] = col[e];
        eval[slot] = val[e];
    }
}

// ---------------------------------------------------------------------------
// SpMM (CSR, gather): one 64-lane wave per row, lane owns 2 features.
// No atomics; z written exactly once per row (rows w/ 0 edges write zeros).
// ---------------------------------------------------------------------------
__global__ __launch_bounds__(256) void spmm_csr(
    const int* __restrict__ rowptr, const int* __restrict__ ecol,
    const float* __restrict__ eval, const float* __restrict__ x,
    float* __restrict__ z, int M)
{
    const int row = blockIdx.x * 4 + (threadIdx.x >> 6);
    if (row >= M) return;
    const int lane = threadIdx.x & 63;

    const int start = (row == 0) ? 0 : rowptr[row - 1];
    const int end   = rowptr[row];

    float2 acc = make_float2(0.f, 0.f);
    int j = start;
    for (; j + 2 <= end; j += 2) {
        int   c0 = ecol[j],   c1 = ecol[j + 1];
        float v0 = eval[j],   v1 = eval[j + 1];
        float2 x0 = *reinterpret_cast<const float2*>(x + (size_t)c0 * FDIM + lane * 2);
        float2 x1 = *reinterpret_cast<const float2*>(x + (size_t)c1 * FDIM + lane * 2);
        acc.x = fmaf(v0, x0.x, acc.x);
        acc.y = fmaf(v0, x0.y, acc.y);
        acc.x = fmaf(v1, x1.x, acc.x);
        acc.y = fmaf(v1, x1.y, acc.y);
    }
    if (j < end) {
        int   c0 = ecol[j];
        float v0 = eval[j];
        float2 x0 = *reinterpret_cast<const float2*>(x + (size_t)c0 * FDIM + lane * 2);
        acc.x = fmaf(v0, x0.x, acc.x);
        acc.y = fmaf(v0, x0.y, acc.y);
    }
    *reinterpret_cast<float2*>(z + (size_t)row * FDIM + lane * 2) = acc;
}

// ---------------------------------------------------------------------------
// GEMM: out[M,128] = z[M,128] @ W[128,128]   (fp32 vector ALU) — unchanged
// ---------------------------------------------------------------------------
__global__ __launch_bounds__(256, 2) void gemm_zw(
    const float* __restrict__ z, const float* __restrict__ w,
    float* __restrict__ out, int M)
{
    __shared__ float sZt[128 * 65];
    __shared__ float sW[64 * 132];

    const int tidx = threadIdx.x;
    const int rowBase = blockIdx.x * 64;

    #pragma unroll
    for (int i = 0; i < 8; ++i) {
        int idx = tidx + 256 * i;
        int r   = idx >> 5;
        int k4  = idx & 31;
        float4 v = make_float4(0.f, 0.f, 0.f, 0.f);
        if (rowBase + r < M)
            v = *reinterpret_cast<const float4*>(
                z + (size_t)(rowBase + r) * FDIM + k4 * 4);
        sZt[(k4 * 4 + 0) * 65 + r] = v.x;
        sZt[(k4 * 4 + 1) * 65 + r] = v.y;
        sZt[(k4 * 4 + 2) * 65 + r] = v.z;
        sZt[(k4 * 4 + 3) * 65 + r] = v.w;
    }

    const int ty = tidx >> 4;
    const int tx = tidx & 15;
    const int r0 = ty * 4;
    const int c0 = tx * 4;

    float acc[4][8] = {};

    for (int kc = 0; kc < 128; kc += 64) {
        __syncthreads();
        #pragma unroll
        for (int i = 0; i < 8; ++i) {
            int idx = tidx + 256 * i;
            int k   = idx >> 5;
            int c4  = idx & 31;
            float4 v = *reinterpret_cast<const float4*>(
                w + (size_t)(kc + k) * FDIM + c4 * 4);
            *reinterpret_cast<float4*>(&sW[k * 132 + c4 * 4]) = v;
        }
        __syncthreads();

        #pragma unroll 8
        for (int kk = 0; kk < 64; ++kk) {
            int k = kc + kk;
            float4 zv = *reinterpret_cast<const float4*>(&sZt[k * 65 + r0]);
            float4 w0 = *reinterpret_cast<const float4*>(&sW[kk * 132 + c0]);
            float4 w1 = *reinterpret_cast<const float4*>(&sW[kk * 132 + c0 + 64]);
            float zr[4] = {zv.x, zv.y, zv.z, zv.w};
            float wv[8] = {w0.x, w0.y, w0.z, w0.w, w1.x, w1.y, w1.z, w1.w};
            #pragma unroll
            for (int i = 0; i < 4; ++i)
                #pragma unroll
                for (int j = 0; j < 8; ++j)
                    acc[i][j] += zr[i] * wv[j];
        }
    }

    #pragma unroll
    for (int i = 0; i < 4; ++i) {
        int r = rowBase + r0 + i;
        if (r < M) {
            float4 o0 = make_float4(acc[i][0], acc[i][1], acc[i][2], acc[i][3]);
            float4 o1 = make_float4(acc[i][4], acc[i][5], acc[i][6], acc[i][7]);
            *reinterpret_cast<float4*>(out + (size_t)r * FDIM + c0)      = o0;
            *reinterpret_cast<float4*>(out + (size_t)r * FDIM + c0 + 64) = o1;
        }
    }
}

extern "C" void kernel_launch(void* const* d_in, const int* in_sizes, int n_in,
                              void* d_out, int out_size, void* d_ws, size_t ws_size,
                              hipStream_t stream) {
    const int*   row = (const int*)d_in[0];
    const int*   col = (const int*)d_in[1];
    const float* val = (const float*)d_in[2];
    const float* x   = (const float*)d_in[3];
    const float* w   = (const float*)d_in[4];
    float* out = (float*)d_out;

    const int E = in_sizes[0];
    const int M = in_sizes[3] / FDIM;   // 100000

    // ---- workspace layout (256B aligned chunks) ----
    char* ws = (char*)d_ws;
    size_t off = 0;
    auto carve = [&](size_t bytes) {
        void* p = ws + off;
        off += (bytes + 255) & ~(size_t)255;
        return p;
    };
    float* z        = (float*)carve((size_t)M * FDIM * sizeof(float)); // 51.2 MB
    int*   rowptr   = (int*)  carve((size_t)M * sizeof(int));
    int*   counts   = (int*)  carve((size_t)M * sizeof(int));
    int*   ecol     = (int*)  carve((size_t)E * sizeof(int));
    float* eval_    = (float*)carve((size_t)E * sizeof(float));
    int*   partials = (int*)  carve(1024 * sizeof(int));

    const int NBLK = (M + 1023) / 1024;   // 98 for M=100000 (<=1024 required)

    hipMemsetAsync(counts, 0, (size_t)M * sizeof(int), stream);

    hist_rows<<<(E + 255) / 256, 256, 0, stream>>>(row, counts, E);
    scan_block<<<NBLK, 256, 0, stream>>>(counts, rowptr, partials, M);
    scan_partials<<<1, 1024, 0, stream>>>(partials, NBLK);
    scan_add<<<NBLK, 256, 0, stream>>>(rowptr, partials, M);
    csr_fill<<<(E + 255) / 256, 256, 0, stream>>>(row, col, val, rowptr,
                                                  ecol, eval_, E);
    spmm_csr<<<(M + 3) / 4, 256, 0, stream>>>(rowptr, ecol, eval_, x, z, M);
    gemm_zw<<<(M + 63) / 64, 256, 0, stream>>>(z, w, out, M);
}